// Round 11
// baseline (17399.969 us; speedup 1.0000x reference)
//
#include <hip/hip_runtime.h>
#include <cstdint>

typedef _Float16 f16;
typedef f16      f16x8 __attribute__((ext_vector_type(8)));
typedef float    f32x4 __attribute__((ext_vector_type(4)));
typedef uint32_t u32;
typedef u32      u32x4 __attribute__((ext_vector_type(4)));

#define NB    32
#define TT    1024
#define DD    512
#define HH    512
#define NBHH  (NB*HH)
#define NWG   16

__device__ __forceinline__ float fsig(float x) {
    return __builtin_amdgcn_rcpf(1.0f + __expf(-x));
}
__device__ __forceinline__ float ftanh(float x) {
    return 1.0f - 2.0f * __builtin_amdgcn_rcpf(__expf(2.0f * x) + 1.0f);
}

// ---- setup kernels -------------------------------------------------------

__global__ void k_cast_x(const float* __restrict__ x, f16* __restrict__ x16) {
    int i = (blockIdx.x * 256 + threadIdx.x) * 8;
    float4 a = *(const float4*)(x + i);
    float4 c = *(const float4*)(x + i + 4);
    f16x8 v;
    v[0] = (f16)a.x; v[1] = (f16)a.y; v[2] = (f16)a.z; v[3] = (f16)a.w;
    v[4] = (f16)c.x; v[5] = (f16)c.y; v[6] = (f16)c.z; v[7] = (f16)c.w;
    *(f16x8*)(x16 + i) = v;
}

// W (512 x 2048 row-major) -> Wp[colp][k] f16; hcol=(colp>>5)*8+((colp&31)>>2),
// gate=colp&3. (Same layout as all prior rounds; works for the fat-WG colp.)
__global__ void k_perm_w(const float* __restrict__ W, f16* __restrict__ Wp) {
    int tid = blockIdx.x * 256 + threadIdx.x;   // 2048*512
    int colp = tid >> 9, k = tid & 511;
    int wg = colp >> 5, c = colp & 31;
    int gate = c & 3, j = c >> 2;
    int col = gate * 512 + wg * 8 + j;
    Wp[tid] = (f16)W[k * 2048 + col];
}

// h0 -> f16 into parity-1 buffer (consumed at t=0); dispatch-boundary coherence.
__global__ void k_h0(const float* __restrict__ h0, f16* __restrict__ hb) {
    int i = blockIdx.x * 256 + threadIdx.x;     // 32*512
    hb[i] = (f16)h0[i];
}

// ---- persistent LSTM kernel ---------------------------------------------
// 16 WGs x 1024 threads (16 waves, one CU each). Monotone per-WG flags (16,
// spread 64B apart), dual-parity h buffers, device scope (sc0 sc1) for all
// cross-WG traffic. Protocol identical to R5/R10; only the participant
// count and per-WG width changed.

__global__ void __launch_bounds__(1024, 1) k_lstm(
    const f16* __restrict__ x16, const f16* __restrict__ Wxp,
    const f16* __restrict__ Whp, const float* __restrict__ bb,
    f16* hbuf, u32* flags, float* __restrict__ out)
{
    __shared__ unsigned char lds_h[32768];   // staged h_{t-1} (swizzled)
    __shared__ u32           lds_pub[1024];  // this WG's h_t slice (32n x 32c)
    __shared__ float         lds_out[8192];  // 8 steps x 1024 out values

    const int wg  = blockIdx.x;              // 0..15
    const int tid = threadIdx.x;             // 0..1023
    const int w   = tid >> 6;                // wave 0..15
    const int l   = tid & 63;
    const int ct  = w >> 1;                  // col-tile 0..7
    const int mt  = w & 1;                   // row block
    const int lq  = l >> 4, lc = l & 15;

    const int colp = wg * 128 + ct * 16 + lc;  // permuted gate column
    const int gate = lc & 3, j_in = lc >> 2;
    const int hcol = wg * 32 + ct * 4 + j_in;
    const int hc32 = ct * 4 + j_in;            // 0..31 within WG slice
    const float bv = bb[gate * 512 + hcol];

    const int arow   = mt * 16 + lc;           // A-fragment row (batch index)
    const int rm     = l & 3;                  // == gate
    const int n_mine = mt * 16 + lq * 4 + rm;  // row this lane produces

    // Wh and Wx fragments resident in VGPRs for the whole sequence.
    f16x8 Bh[16], Bx[16];
    {
        const f16* ph = Whp + (size_t)colp * 512 + lq * 8;
        const f16* px = Wxp + (size_t)colp * 512 + lq * 8;
        #pragma unroll
        for (int ks = 0; ks < 16; ++ks) {
            Bh[ks] = *(const f16x8*)(ph + ks * 32);
            Bx[ks] = *(const f16x8*)(px + ks * 32);
        }
    }

    const f16* xptr = x16 + (size_t)arow * (TT * DD) + lq * 8;

    // stage mapping: thread covers 32B of row srow
    const int srow  = tid >> 5;              // 0..31
    const int sbyte = (tid & 31) * 32;       // byte offset within 1KB row

    float c_reg[4] = {0.f, 0.f, 0.f, 0.f};

    for (int t = 0; t < TT; ++t) {
        // ---- x_t @ Wx + b : independent of h, overlaps others' tails
        f32x4 acc = {bv, bv, bv, bv};
        {
            const f16* xp = xptr + (size_t)t * DD;
            #pragma unroll
            for (int ks = 0; ks < 16; ++ks) {
                f16x8 ax = *(const f16x8*)(xp + ks * 32);
                acc = __builtin_amdgcn_mfma_f32_16x16x32_f16(ax, Bx[ks], acc, 0, 0, 0);
            }
        }
        // ---- poll: wave0 only (16 flags, 64B apart); others at barrier
        if (t) {
            if (w == 0) {
                const u32* fl = flags + (l & 15) * 16;
                int guard = 0;
                for (;;) {
                    u32 f;
                    asm volatile("global_load_dword %0, %1, off sc0 sc1"
                                 : "=v"(f) : "v"(fl));
                    asm volatile("s_waitcnt vmcnt(0)" ::: "memory");
                    if (__all(f >= (u32)t) || ++guard > (1 << 20)) break;
                    __builtin_amdgcn_s_sleep(1);
                }
            }
            __syncthreads();
        }
        __builtin_amdgcn_sched_barrier(0);
        // ---- cooperative stage: full 32KB h_{t-1} -> LDS (32B/thread)
        {
            const char* gp = (const char*)(hbuf + ((t & 1) ? 0 : NBHH))
                           + srow * 1024 + sbyte;
            u32x4 h0v, h1v;
            asm volatile("global_load_dwordx4 %0, %1, off sc0 sc1"
                         : "=v"(h0v) : "v"(gp));
            asm volatile("global_load_dwordx4 %0, %1, off offset:16 sc0 sc1"
                         : "=v"(h1v) : "v"(gp));
            asm volatile("s_waitcnt vmcnt(0)" ::: "memory");
            __builtin_amdgcn_sched_barrier(0);
            const int swz = (srow & 7) << 4;
            *(u32x4*)&lds_h[srow * 1024 + ((sbyte)      ^ swz)] = h0v;
            *(u32x4*)&lds_h[srow * 1024 + ((sbyte + 16) ^ swz)] = h1v;
        }
        __syncthreads();
        // ---- h_{t-1} @ Wh from LDS (2-way banked via XOR swizzle)
        {
            const int swz   = (arow & 7) << 4;
            const int baseA = arow * 1024;
            #pragma unroll
            for (int ks = 0; ks < 16; ++ks) {
                int inrowA = lq * 16 + ks * 64;
                u32x4 a = *(const u32x4*)&lds_h[baseA + (inrowA ^ swz)];
                acc = __builtin_amdgcn_mfma_f32_16x16x32_f16(
                          __builtin_bit_cast(f16x8, a), Bh[ks], acc, 0, 0, 0);
            }
        }
        // ---- gates (quad-redundant c state, intra-quad shuffles)
        float hv = 0.f;
        #pragma unroll
        for (int r = 0; r < 4; ++r) {
            float av = acc[r];
            int base = l & ~3;
            float ai = __shfl(av, base | 0, 64);
            float af = __shfl(av, base | 1, 64);
            float ao = __shfl(av, base | 2, 64);
            float ag = __shfl(av, base | 3, 64);
            float ig = fsig(ai), fg = fsig(af), og = fsig(ao), gg = ftanh(ag);
            float cn = fg * c_reg[r] + ig * gg;
            c_reg[r] = cn;
            float h = og * ftanh(cn);
            if (r == rm) hv = h;
        }
        // ---- stage h_t slice + out value in LDS
        {
            f16 h16 = (f16)hv;
            lds_pub[n_mine * 32 + hc32] = (u32)__builtin_bit_cast(unsigned short, h16);
            lds_out[(t & 7) * 1024 + n_mine * 32 + hc32] = hv;
        }
        __syncthreads();
        // ---- wave0: publish WG slice (32 rows x 64B) as 2x16B/lane, drain, flag
        if (w == 0) {
            const int r0   = l >> 2;            // rows r0 and r0+16
            const int part = l & 3;
            #pragma unroll
            for (int half = 0; half < 2; ++half) {
                int row = r0 + half * 16;
                const u32* pp = lds_pub + row * 32 + part * 8;
                u32 p0 = (pp[0] & 0xffffu) | (pp[1] << 16);
                u32 p1 = (pp[2] & 0xffffu) | (pp[3] << 16);
                u32 p2 = (pp[4] & 0xffffu) | (pp[5] << 16);
                u32 p3 = (pp[6] & 0xffffu) | (pp[7] << 16);
                u32x4 pv = {p0, p1, p2, p3};
                f16* hdst = hbuf + ((t & 1) ? NBHH : 0)
                          + row * HH + wg * 32 + part * 8;
                asm volatile("global_store_dwordx4 %0, %1, off sc0 sc1"
                             :: "v"(hdst), "v"(pv) : "memory");
            }
            asm volatile("s_waitcnt vmcnt(0)" ::: "memory");
            if (l == 0) {
                u32 fv = (u32)(t + 1);
                u32* mf = flags + wg * 16;
                asm volatile("global_store_dword %0, %1, off sc0 sc1"
                             :: "v"(mf), "v"(fv) : "memory");
            }
        }
        // ---- flush 8 steps of out (plain cached float4, off hot path)
        if ((t & 7) == 7) {
            #pragma unroll
            for (int k2 = 0; k2 < 2; ++k2) {
                int tau = tid + 1024 * k2;        // s*256 + row*8 + cq
                int s   = tau >> 8;
                int q4  = tau & 255;
                int row = q4 >> 3;
                int cq  = q4 & 7;
                float4 v = *(const float4*)&lds_out[s * 1024 + row * 32 + cq * 4];
                float* op = out + (size_t)row * (TT * HH)
                                + (size_t)(t - 7 + s) * HH + wg * 32 + cq * 4;
                *(float4*)op = v;
            }
        }
    }
}

// ---- launch --------------------------------------------------------------

extern "C" void kernel_launch(void* const* d_in, const int* in_sizes, int n_in,
                              void* d_out, int out_size, void* d_ws, size_t ws_size,
                              hipStream_t stream)
{
    (void)in_sizes; (void)n_in; (void)out_size; (void)ws_size;
    const float* x  = (const float*)d_in[0];
    const float* h0 = (const float*)d_in[1];
    const float* Wx = (const float*)d_in[2];
    const float* Wh = (const float*)d_in[3];
    const float* b  = (const float*)d_in[4];
    float* out = (float*)d_out;

    char* ws = (char*)d_ws;
    u32* flags = (u32*)ws;                               // 4 KiB reserved
    f16* x16   = (f16*)(ws + (4 << 10));                 // 32 MiB
    f16* Wxp   = (f16*)(ws + (4 << 10) + (32 << 20));    // 2 MiB
    f16* Whp   = (f16*)(ws + (4 << 10) + (34 << 20));    // 2 MiB
    f16* hbuf  = (f16*)(ws + (4 << 10) + (36 << 20));    // 2 x 64 KiB

    hipMemsetAsync(flags, 0, 4096, stream);
    k_cast_x<<<8192, 256, 0, stream>>>(x, x16);
    k_perm_w<<<4096, 256, 0, stream>>>(Wx, Wxp);
    k_perm_w<<<4096, 256, 0, stream>>>(Wh, Whp);
    k_h0<<<64, 256, 0, stream>>>(h0, hbuf + NBHH);       // parity 1 = h_{-1}
    k_lstm<<<NWG, 1024, 0, stream>>>(x16, Wxp, Whp, b, hbuf, flags, out);
}

// Round 12
// 6267.501 us; speedup vs baseline: 2.7762x; 2.7762x over previous
//
#include <hip/hip_runtime.h>
#include <cstdint>

typedef _Float16 f16;
typedef f16      f16x8 __attribute__((ext_vector_type(8)));
typedef float    f32x4 __attribute__((ext_vector_type(4)));
typedef uint32_t u32;
typedef u32      u32x4 __attribute__((ext_vector_type(4)));

#define NB    32
#define TT    1024
#define DD    512
#define HH    512
#define NBHH  (NB*HH)
#define NWG   32

__device__ __forceinline__ float fsig(float x) {
    return __builtin_amdgcn_rcpf(1.0f + __expf(-x));
}
__device__ __forceinline__ float ftanh(float x) {
    return 1.0f - 2.0f * __builtin_amdgcn_rcpf(__expf(2.0f * x) + 1.0f);
}

// ---- setup kernels -------------------------------------------------------

__global__ void k_cast_x(const float* __restrict__ x, f16* __restrict__ x16) {
    int i = (blockIdx.x * 256 + threadIdx.x) * 8;
    float4 a = *(const float4*)(x + i);
    float4 c = *(const float4*)(x + i + 4);
    f16x8 v;
    v[0] = (f16)a.x; v[1] = (f16)a.y; v[2] = (f16)a.z; v[3] = (f16)a.w;
    v[4] = (f16)c.x; v[5] = (f16)c.y; v[6] = (f16)c.z; v[7] = (f16)c.w;
    *(f16x8*)(x16 + i) = v;
}

// W (512 x 2048 row-major) -> Wp[colp][k] f16; hcol=(colp>>5)*8+((colp&31)>>2),
// gate=colp&3. (Unchanged; valid for any WG width over colp.)
__global__ void k_perm_w(const float* __restrict__ W, f16* __restrict__ Wp) {
    int tid = blockIdx.x * 256 + threadIdx.x;   // 2048*512
    int colp = tid >> 9, k = tid & 511;
    int wg = colp >> 5, c = colp & 31;
    int gate = c & 3, j = c >> 2;
    int col = gate * 512 + wg * 8 + j;
    Wp[tid] = (f16)W[k * 2048 + col];
}

// h0 -> f16 into parity-1 buffer (consumed at t=0); dispatch-boundary coherence.
__global__ void k_h0(const float* __restrict__ h0, f16* __restrict__ hb) {
    int i = blockIdx.x * 256 + threadIdx.x;     // 32*512
    hb[i] = (f16)h0[i];
}

// ---- persistent LSTM kernel ---------------------------------------------
// 32 WGs x 512 threads (8 waves). Monotone per-WG flags (32), dual-parity h,
// device scope (sc0 sc1). Protocol identical to R10; only participant count
// and per-WG width changed. __launch_bounds__(512,2) -> 256-VGPR cap, no
// spill of the 128-VGPR resident weight fragments (R11's failure mode).

__global__ void __launch_bounds__(512, 2) k_lstm(
    const f16* __restrict__ x16, const f16* __restrict__ Wxp,
    const f16* __restrict__ Whp, const float* __restrict__ bb,
    f16* hbuf, u32* flags, float* __restrict__ out)
{
    __shared__ unsigned char lds_h[32768];   // staged h_{t-1} (swizzled)
    __shared__ u32           lds_pub[512];   // 32 rows x 16 hcols
    __shared__ float         lds_out[4096];  // 8 steps x 512 out values

    const int wg  = blockIdx.x;              // 0..31
    const int tid = threadIdx.x;             // 0..511
    const int w   = tid >> 6;                // wave 0..7
    const int l   = tid & 63;
    const int ct  = w >> 1;                  // col-tile 0..3
    const int mt  = w & 1;                   // row block
    const int lq  = l >> 4, lc = l & 15;

    const int colp = wg * 64 + ct * 16 + lc;   // permuted gate column
    const int gate = lc & 3, j_in = lc >> 2;
    const int hc16 = (ct >> 1) * 8 + (ct & 1) * 4 + j_in;  // 0..15 in WG slice
    const int hcol = wg * 16 + hc16;
    const float bv = bb[gate * 512 + hcol];

    const int arow   = mt * 16 + lc;           // A-fragment row (batch index)
    const int rm     = l & 3;                  // == gate
    const int n_mine = mt * 16 + lq * 4 + rm;  // row this lane produces

    // Wh and Wx fragments resident in VGPRs for the whole sequence.
    f16x8 Bh[16], Bx[16];
    {
        const f16* ph = Whp + (size_t)colp * 512 + lq * 8;
        const f16* px = Wxp + (size_t)colp * 512 + lq * 8;
        #pragma unroll
        for (int ks = 0; ks < 16; ++ks) {
            Bh[ks] = *(const f16x8*)(ph + ks * 32);
            Bx[ks] = *(const f16x8*)(px + ks * 32);
        }
    }

    const f16* xptr = x16 + (size_t)arow * (TT * DD) + lq * 8;

    float c_reg[4] = {0.f, 0.f, 0.f, 0.f};

    for (int t = 0; t < TT; ++t) {
        // ---- x_t @ Wx + b : independent of h, overlaps others' tails
        f32x4 acc = {bv, bv, bv, bv};
        {
            const f16* xp = xptr + (size_t)t * DD;
            #pragma unroll
            for (int ks = 0; ks < 16; ++ks) {
                f16x8 ax = *(const f16x8*)(xp + ks * 32);
                acc = __builtin_amdgcn_mfma_f32_16x16x32_f16(ax, Bx[ks], acc, 0, 0, 0);
            }
        }
        // ---- poll: wave0 only (32 flags, lanes duplicate-read); backoff
        if (t) {
            if (w == 0) {
                const u32* fl = flags + (l & 31);
                int guard = 0;
                for (;;) {
                    u32 f;
                    asm volatile("global_load_dword %0, %1, off sc0 sc1"
                                 : "=v"(f) : "v"(fl));
                    asm volatile("s_waitcnt vmcnt(0)" ::: "memory");
                    if (__all(f >= (u32)t) || ++guard > (1 << 20)) break;
                    __builtin_amdgcn_s_sleep(1);
                }
            }
            __syncthreads();
        }
        __builtin_amdgcn_sched_barrier(0);
        // ---- cooperative stage: 32KB h_{t-1} -> LDS, 16B granules (R5 map)
        {
            const char* gp = (const char*)(hbuf + ((t & 1) ? 0 : NBHH)) + tid * 16;
            u32x4 hv4[4];
            #pragma unroll
            for (int r = 0; r < 4; ++r) {
                const char* p = gp + r * 8192;
                asm volatile("global_load_dwordx4 %0, %1, off sc0 sc1"
                             : "=v"(hv4[r]) : "v"(p));
            }
            asm volatile("s_waitcnt vmcnt(0)" ::: "memory");
            __builtin_amdgcn_sched_barrier(0);
            const int inrow = (tid & 63) * 16;
            #pragma unroll
            for (int r = 0; r < 4; ++r) {
                int row = (tid >> 6) + 8 * r;
                int off = row * 1024 + (inrow ^ ((row & 7) << 4));
                *(u32x4*)&lds_h[off] = hv4[r];
            }
        }
        __syncthreads();
        // ---- h_{t-1} @ Wh from LDS (2-way banked via XOR swizzle)
        {
            const int swz   = (arow & 7) << 4;
            const int baseA = arow * 1024;
            #pragma unroll
            for (int ks = 0; ks < 16; ++ks) {
                int inrowA = lq * 16 + ks * 64;
                u32x4 a = *(const u32x4*)&lds_h[baseA + (inrowA ^ swz)];
                acc = __builtin_amdgcn_mfma_f32_16x16x32_f16(
                          __builtin_bit_cast(f16x8, a), Bh[ks], acc, 0, 0, 0);
            }
        }
        // ---- gates (quad-redundant c state, intra-quad shuffles)
        float hv = 0.f;
        #pragma unroll
        for (int r = 0; r < 4; ++r) {
            float av = acc[r];
            int base = l & ~3;
            float ai = __shfl(av, base | 0, 64);
            float af = __shfl(av, base | 1, 64);
            float ao = __shfl(av, base | 2, 64);
            float ag = __shfl(av, base | 3, 64);
            float ig = fsig(ai), fg = fsig(af), og = fsig(ao), gg = ftanh(ag);
            float cn = fg * c_reg[r] + ig * gg;
            c_reg[r] = cn;
            float h = og * ftanh(cn);
            if (r == rm) hv = h;
        }
        // ---- stage h_t slice + out value in LDS
        {
            f16 h16 = (f16)hv;
            lds_pub[n_mine * 16 + hc16] = (u32)__builtin_bit_cast(unsigned short, h16);
            lds_out[(t & 7) * 512 + n_mine * 16 + hc16] = hv;
        }
        __syncthreads();
        // ---- wave0: publish 32 rows x 32B as 1x16B/lane, drain, flag
        if (w == 0) {
            {
                const int row = l >> 1, half = l & 1;
                const u32* pp = lds_pub + row * 16 + half * 8;
                u32 p0 = (pp[0] & 0xffffu) | (pp[1] << 16);
                u32 p1 = (pp[2] & 0xffffu) | (pp[3] << 16);
                u32 p2 = (pp[4] & 0xffffu) | (pp[5] << 16);
                u32 p3 = (pp[6] & 0xffffu) | (pp[7] << 16);
                u32x4 pv = {p0, p1, p2, p3};
                f16* hdst = hbuf + ((t & 1) ? NBHH : 0)
                          + row * HH + wg * 16 + half * 8;
                asm volatile("global_store_dwordx4 %0, %1, off sc0 sc1"
                             :: "v"(hdst), "v"(pv) : "memory");
            }
            asm volatile("s_waitcnt vmcnt(0)" ::: "memory");
            if (l == 0) {
                u32 fv = (u32)(t + 1);
                u32* mf = flags + wg;
                asm volatile("global_store_dword %0, %1, off sc0 sc1"
                             :: "v"(mf), "v"(fv) : "memory");
            }
        }
        // ---- flush 8 steps of out (plain cached float4, off hot path)
        if ((t & 7) == 7) {
            #pragma unroll
            for (int k2 = 0; k2 < 2; ++k2) {
                int tau = tid + 512 * k2;         // s*128 + row*4 + cq
                int s   = tau >> 7;
                int rem = tau & 127;
                int row = rem >> 2;
                int cq  = rem & 3;
                float4 v = *(const float4*)&lds_out[s * 512 + row * 16 + cq * 4];
                float* op = out + (size_t)row * (TT * HH)
                                + (size_t)(t - 7 + s) * HH + wg * 16 + cq * 4;
                *(float4*)op = v;
            }
        }
    }
}

// ---- launch --------------------------------------------------------------

extern "C" void kernel_launch(void* const* d_in, const int* in_sizes, int n_in,
                              void* d_out, int out_size, void* d_ws, size_t ws_size,
                              hipStream_t stream)
{
    (void)in_sizes; (void)n_in; (void)out_size; (void)ws_size;
    const float* x  = (const float*)d_in[0];
    const float* h0 = (const float*)d_in[1];
    const float* Wx = (const float*)d_in[2];
    const float* Wh = (const float*)d_in[3];
    const float* b  = (const float*)d_in[4];
    float* out = (float*)d_out;

    char* ws = (char*)d_ws;
    u32* flags = (u32*)ws;                               // 4 KiB reserved
    f16* x16   = (f16*)(ws + (4 << 10));                 // 32 MiB
    f16* Wxp   = (f16*)(ws + (4 << 10) + (32 << 20));    // 2 MiB
    f16* Whp   = (f16*)(ws + (4 << 10) + (34 << 20));    // 2 MiB
    f16* hbuf  = (f16*)(ws + (4 << 10) + (36 << 20));    // 2 x 64 KiB

    hipMemsetAsync(flags, 0, 4096, stream);
    k_cast_x<<<8192, 256, 0, stream>>>(x, x16);
    k_perm_w<<<4096, 256, 0, stream>>>(Wx, Wxp);
    k_perm_w<<<4096, 256, 0, stream>>>(Wh, Whp);
    k_h0<<<64, 256, 0, stream>>>(h0, hbuf + NBHH);       // parity 1 = h_{-1}
    k_lstm<<<NWG, 512, 0, stream>>>(x16, Wxp, Whp, b, hbuf, flags, out);
}